// Round 2
// baseline (526.059 us; speedup 1.0000x reference)
//
#include <hip/hip_runtime.h>

#define NETS 32
#define BATCH 4096
#define D0 256
#define D1 512
#define D2 512
#define D3 128
#define MT 32            // batch rows per block
#define LDA (D0 + 8)     // 264 halves -> 528 B row stride (4-bank rotation)
#define LDH (D1 + 8)     // 520 halves -> 1040 B row stride (4-bank rotation)

using half8 = __attribute__((ext_vector_type(8))) _Float16;
using half4 = __attribute__((ext_vector_type(4))) _Float16;
using f32x4 = __attribute__((ext_vector_type(4))) float;

// ---------------- fp32 -> fp16 cast kernel (each thread: 4 elems) ----------------
__global__ void cvt_f32_f16(const float* __restrict__ src, _Float16* __restrict__ dst, int n4) {
    int i = blockIdx.x * blockDim.x + threadIdx.x;
    if (i < n4) {
        float4 v = reinterpret_cast<const float4*>(src)[i];
        half4 o;
        o[0] = (_Float16)v.x; o[1] = (_Float16)v.y;
        o[2] = (_Float16)v.z; o[3] = (_Float16)v.w;
        reinterpret_cast<half4*>(dst)[i] = o;
    }
}

// ---------------- fused 3-layer MLP ----------------
// Per block: one net, MT batch rows. Wave w owns N-range [w*128,(w+1)*128) for L1/L2,
// [w*32,(w+1)*32) for L3. A-frags from LDS, B-frags (weights) straight from global (L2).

template<int K, int NFRAG>
__device__ __forceinline__ void layer_mfma(const _Float16* As, int lda,
                                           const _Float16* __restrict__ Wg,
                                           int n_base, int lane16, int quad,
                                           f32x4 acc[2][NFRAG]) {
    for (int kk = 0; kk < K / 32; ++kk) {
        half8 a[2];
#pragma unroll
        for (int mi = 0; mi < 2; ++mi)
            a[mi] = *reinterpret_cast<const half8*>(As + (mi * 16 + lane16) * lda + kk * 32 + quad * 8);
#pragma unroll
        for (int ni = 0; ni < NFRAG; ++ni) {
            half8 b = *reinterpret_cast<const half8*>(Wg + (n_base + ni * 16 + lane16) * K + kk * 32 + quad * 8);
#pragma unroll
            for (int mi = 0; mi < 2; ++mi)
                acc[mi][ni] = __builtin_amdgcn_mfma_f32_16x16x32_f16(a[mi], b, acc[mi][ni], 0, 0, 0);
        }
    }
}

template<int NFRAG>
__device__ __forceinline__ void store_act(f32x4 acc[2][NFRAG], const float* __restrict__ bias,
                                          _Float16* dst, int ldd, int n_base,
                                          int lane16, int quad) {
#pragma unroll
    for (int ni = 0; ni < NFRAG; ++ni) {
        float bv = bias[n_base + ni * 16 + lane16];
        int col = n_base + ni * 16 + lane16;
#pragma unroll
        for (int mi = 0; mi < 2; ++mi) {
#pragma unroll
            for (int r = 0; r < 4; ++r) {
                float v = acc[mi][ni][r] + bv;
                v = fmaxf(v, 0.0f);                        // relu
                int row = mi * 16 + quad * 4 + r;
                dst[row * ldd + col] = (_Float16)v;
            }
        }
    }
}

__global__ __launch_bounds__(256, 2) void mlp_fused(
    const _Float16* __restrict__ Xh,
    const _Float16* __restrict__ W1h, const float* __restrict__ b1,
    const _Float16* __restrict__ W2h, const float* __restrict__ b2,
    const _Float16* __restrict__ W3h, const float* __restrict__ b3,
    float* __restrict__ out) {
    __shared__ __align__(16) _Float16 bufA[MT * LDH];  // X tile (LDA layout), later H2 (LDH)
    __shared__ __align__(16) _Float16 bufB[MT * LDH];  // H1

    const int tid = threadIdx.x;
    const int w = tid >> 6;
    const int l = tid & 63;
    const int lane16 = l & 15;
    const int quad = l >> 4;

    // XCD-locality swizzle: dispatch round-robins blockIdx over 8 XCDs ->
    // pin 4 nets per XCD so each XCD-L2 holds ~3.7 MB of weights.
    const int bb = blockIdx.x;
    const int xcd = bb & 7;
    const int s = bb >> 3;                // 0..511
    const int net = xcd * 4 + (s >> 7);   // 0..31
    const int mt = s & 127;               // 0..127
    const int m0 = mt * MT;

    // ---- stage X tile [MT][D0] into bufA (16B vector copies) ----
    // MT*D0/8 = 32*32 = 1024 chunks of 8 halves; 256 threads -> 4 iterations.
    {
        const _Float16* xsrc = Xh + (size_t)m0 * D0;
#pragma unroll
        for (int it = 0; it < 4; ++it) {
            int chunk = it * 256 + tid;   // 0..1023 ; 32 chunks of 8 halves per row
            int row = chunk >> 5;
            int c8 = chunk & 31;
            uint4 v = *reinterpret_cast<const uint4*>(xsrc + row * D0 + c8 * 8);
            *reinterpret_cast<uint4*>(&bufA[row * LDA + c8 * 8]) = v;
        }
    }
    __syncthreads();

    // ---- layer 1: H1 = relu(X @ W1^T + b1), K=256, N=512 ----
    {
        f32x4 acc[2][8] = {};
        layer_mfma<D0, 8>(bufA, LDA, W1h + (size_t)net * D1 * D0, w * 128, lane16, quad, acc);
        store_act<8>(acc, b1 + net * D1, bufB, LDH, w * 128, lane16, quad);
    }
    __syncthreads();

    // ---- layer 2: H2 = relu(H1 @ W2^T + b2), K=512, N=512 ----
    {
        f32x4 acc[2][8] = {};
        layer_mfma<D1, 8>(bufB, LDH, W2h + (size_t)net * D2 * D1, w * 128, lane16, quad, acc);
        store_act<8>(acc, b2 + net * D2, bufA, LDH, w * 128, lane16, quad);
    }
    __syncthreads();

    // ---- layer 3: out = H2 @ W3^T + b3, K=512, N=128, fp32 direct to global ----
    {
        f32x4 acc[2][2] = {};
        layer_mfma<D2, 2>(bufA, LDH, W3h + (size_t)net * D3 * D2, w * 32, lane16, quad, acc);
        const int n_base = w * 32;
#pragma unroll
        for (int ni = 0; ni < 2; ++ni) {
            float bv = b3[net * D3 + n_base + ni * 16 + lane16];
            int col = net * D3 + n_base + ni * 16 + lane16;
#pragma unroll
            for (int mi = 0; mi < 2; ++mi) {
#pragma unroll
                for (int r = 0; r < 4; ++r) {
                    int row = m0 + mi * 16 + quad * 4 + r;
                    out[(size_t)row * (NETS * D3) + col] = acc[mi][ni][r] + bv;
                }
            }
        }
    }
}

extern "C" void kernel_launch(void* const* d_in, const int* in_sizes, int n_in,
                              void* d_out, int out_size, void* d_ws, size_t ws_size,
                              hipStream_t stream) {
    const float* x  = (const float*)d_in[0];
    const float* W1 = (const float*)d_in[1];
    const float* b1 = (const float*)d_in[2];
    const float* W2 = (const float*)d_in[3];
    const float* b2 = (const float*)d_in[4];
    const float* W3 = (const float*)d_in[5];
    const float* b3 = (const float*)d_in[6];
    float* out = (float*)d_out;

    // ws layout (fp16): Xh | W1h | W2h | W3h  = ~30 MB total
    _Float16* Xh  = (_Float16*)d_ws;
    _Float16* W1h = Xh  + (size_t)BATCH * D0;          // 1,048,576 elems
    _Float16* W2h = W1h + (size_t)NETS * D1 * D0;      // 4,194,304
    _Float16* W3h = W2h + (size_t)NETS * D2 * D1;      // 8,388,608
                                                       // W3h: 2,097,152

    const int xN  = BATCH * D0;
    const int w1N = NETS * D1 * D0;
    const int w2N = NETS * D2 * D1;
    const int w3N = NETS * D3 * D2;

    cvt_f32_f16<<<xN  / 1024, 256, 0, stream>>>(x,  Xh,  xN  / 4);
    cvt_f32_f16<<<w1N / 1024, 256, 0, stream>>>(W1, W1h, w1N / 4);
    cvt_f32_f16<<<w2N / 1024, 256, 0, stream>>>(W2, W2h, w2N / 4);
    cvt_f32_f16<<<w3N / 1024, 256, 0, stream>>>(W3, W3h, w3N / 4);

    mlp_fused<<<NETS * (BATCH / MT), 256, 0, stream>>>(Xh, W1h, b1, W2h, b2, W3h, b3, out);
}